// Round 11
// baseline (35591.705 us; speedup 1.0000x reference)
//
#include <hip/hip_runtime.h>
#include <hip/hip_bf16.h>
#include <stdint.h>

// ---------------------------------------------------------------------------
// Persistent-kernel LSTM decoder for MI355X — v11: v10's decoupled rings
// (proven) + dense staged output. fc writes frames[t][col][m] (f32, 40KB/step)
// into the t-major enc region (slot t dead after step t); k_out transposes to
// out[b][m][t] coalesced afterwards. Kills the 58x scattered-HBM write
// amplification that sat on the ring critical path.
//   g1@s: own>=s+1, g2>=s+1 (h1 ring-3 reuse guard)
//   g2@s: g1>=s,   own>=s+1 (computes gates2[s-2], fc frame[s-3])
// ---------------------------------------------------------------------------

#define NSUP 2003

typedef __attribute__((ext_vector_type(8))) short bf16x8;
typedef __attribute__((ext_vector_type(4))) float f32x4;

// ws layout (bytes)
#define OFF_WTXT   0ull
#define OFF_WHH1   8388608ull
#define OFF_WPREV  16777216ull
#define OFF_WIH2   17825792ull
#define OFF_WHH2   26214400ull
#define OFF_FCW    34603008ull
#define OFF_BIAS2  34799616ull
#define OFF_PSTYLE 34816000ull
#define OFF_ENCB   36913152ull    // t-major enc: 399 x [128 col][1024 u] bf16; frames overlay
#define OFF_ENC399 141508608ull   // pinned enc[:,399,:]  (256KB)
#define OFF_STYLET 36913152ull    // scratch inside ENCB, consumed before k_pack_enc
#define OFF_PREV   141770752ull
#define OFF_H1     207306752ull   // 3 slots x 262144
#define OFF_H2     208093184ull   // 2 slots x 262144
#define OFF_EPG1   208617472ull   // g1 epoch slots: 2cg x 64 x 64B
#define OFF_EPG2   208625664ull   // g2 epoch slots
#define WS_NEED    208717824ull

__device__ __forceinline__ unsigned short f2bf(float f) {
  __hip_bfloat16 b = __float2bfloat16(f);
  return *reinterpret_cast<unsigned short*>(&b);
}
__device__ __forceinline__ float sigm(float x) { return 1.f / (1.f + __expf(-x)); }
__device__ __forceinline__ float tanh_(float x) {
  x = fminf(15.f, fmaxf(-15.f, x));
  float e = __expf(2.f * x);
  return (e - 1.f) / (e + 1.f);
}
__device__ __forceinline__ int origRow(int rp) {
  return ((rp >> 4) & 3) * 1024 + (rp >> 6) * 16 + (rp & 15);
}

#define VMW(n) asm volatile("s_waitcnt vmcnt(" #n ")" ::: "memory")

__device__ __forceinline__ void ldx4(bf16x8& d, const void* p) {      // plain
  asm volatile("global_load_dwordx4 %0, %1, off" : "=v"(d) : "v"(p));
}
__device__ __forceinline__ void ldx4a(bf16x8& d, const void* p) {     // agent
  asm volatile("global_load_dwordx4 %0, %1, off sc1" : "=v"(d) : "v"(p));
}

// ------------------------------- pack kernels -------------------------------
__global__ void k_pack_w1(const float* __restrict__ wih1, const float* __restrict__ whh1,
                          unsigned char* __restrict__ ws) {
  int idx = blockIdx.x * 256 + threadIdx.x;            // 4096*1024
  int rp = idx >> 10, k = idx & 1023;
  int orig = origRow(rp);
  ((unsigned short*)(ws + OFF_WTXT))[idx] = f2bf(wih1[(size_t)orig * 1424 + k]);
  ((unsigned short*)(ws + OFF_WHH1))[idx] = f2bf(whh1[(size_t)orig * 1024 + k]);
}
__global__ void k_pack_w2(const float* __restrict__ wih2, const float* __restrict__ whh2,
                          unsigned char* __restrict__ ws) {
  int idx = blockIdx.x * 256 + threadIdx.x;
  int rp = idx >> 10, k = idx & 1023;
  int orig = origRow(rp);
  ((unsigned short*)(ws + OFF_WIH2))[idx] = f2bf(wih2[(size_t)orig * 1024 + k]);
  ((unsigned short*)(ws + OFF_WHH2))[idx] = f2bf(whh2[(size_t)orig * 1024 + k]);
}
__global__ void k_bias2(const float* __restrict__ bih2, const float* __restrict__ bhh2,
                        unsigned char* __restrict__ ws) {
  int rp = blockIdx.x * 256 + threadIdx.x;
  if (rp >= 4096) return;
  int orig = origRow(rp);
  ((float*)(ws + OFF_BIAS2))[rp] = bih2[orig] + bhh2[orig];
}
__global__ void k_pack_wprev(const float* __restrict__ wih1, unsigned char* __restrict__ ws) {
  int idx = blockIdx.x * 256 + threadIdx.x;            // 4096*128
  int rp = idx >> 7, k = idx & 127;
  int orig = origRow(rp);
  ((unsigned short*)(ws + OFF_WPREV))[idx] =
      (k < 80) ? f2bf(wih1[(size_t)orig * 1424 + 1344 + k]) : (unsigned short)0;
}
__global__ void k_pack_fc(const float* __restrict__ fcw, unsigned char* __restrict__ ws) {
  int idx = blockIdx.x * 256 + threadIdx.x;            // 96*1024
  int r = idx >> 10, k = idx & 1023;
  ((unsigned short*)(ws + OFF_FCW))[idx] =
      (r < 80) ? f2bf(fcw[(size_t)r * 1024 + k]) : (unsigned short)0;
}
// t-major enc pack: encB[t][col][u] for t<399; enc399[col][u] pinned
__global__ void k_pack_enc(const float* __restrict__ enc, unsigned char* __restrict__ ws) {
  size_t i = (size_t)blockIdx.x * 256 + threadIdx.x;   // 13,107,200 float4's
  float4 v = ((const float4*)enc)[i];
  union { unsigned short u[4]; unsigned long long ll; } z;
  z.u[0] = f2bf(v.x); z.u[1] = f2bf(v.y); z.u[2] = f2bf(v.z); z.u[3] = f2bf(v.w);
  int u4 = (int)(i & 255);                // u = u4*4
  int t  = (int)((i >> 8) % 400);
  int b  = (int)(i / (256 * 400));
  unsigned char* dst = (t < 399)
      ? ws + OFF_ENCB + (size_t)t * 262144 + (size_t)b * 2048 + (size_t)u4 * 8
      : ws + OFF_ENC399 + (size_t)b * 2048 + (size_t)u4 * 8;
  *(unsigned long long*)dst = z.ll;
}
__global__ void k_styleT(const float* __restrict__ style, float* __restrict__ sT) {
  int idx = blockIdx.x * 256 + threadIdx.x;            // 320*128
  int j = idx >> 7, n = idx & 127;
  sT[idx] = style[n * 320 + j];
}
__global__ void k_pstyle(const float* __restrict__ wih1, const float* __restrict__ bih1,
                         const float* __restrict__ bhh1, const float* __restrict__ sT,
                         unsigned char* __restrict__ ws) {
  int n = threadIdx.x & 127, rsub = threadIdx.x >> 7;
  int rp = blockIdx.x * 2 + rsub;
  int orig = origRow(rp);
  const float* wr = wih1 + (size_t)orig * 1424 + 1024;
  float a0 = 0.f, a1 = 0.f, a2 = 0.f, a3 = 0.f;
  for (int j = 0; j < 320; j += 4) {
    a0 += wr[j + 0] * sT[(j + 0) * 128 + n];
    a1 += wr[j + 1] * sT[(j + 1) * 128 + n];
    a2 += wr[j + 2] * sT[(j + 2) * 128 + n];
    a3 += wr[j + 3] * sT[(j + 3) * 128 + n];
  }
  ((float*)(ws + OFF_PSTYLE))[rp * 128 + n] = (a0 + a1) + (a2 + a3) + bih1[orig] + bhh1[orig];
}
__global__ void k_pack_prev(const float* __restrict__ mel, unsigned char* __restrict__ ws) {
  __shared__ unsigned short pl[64][80];
  int b = blockIdx.y, tt0 = blockIdx.x * 64;
  int tid = threadIdx.x;
  int ttl = tid & 63, mi = tid >> 6;
  for (int m = mi; m < 80; m += 4) {
    int tau = tt0 + ttl;
    if (tau <= 1998) pl[ttl][m] = f2bf(mel[((size_t)b * 80 + m) * 2000 + tau]);
  }
  __syncthreads();
  unsigned short* pv = (unsigned short*)(ws + OFF_PREV);
  for (int idx = tid; idx < 64 * 80; idx += 256) {
    int t2 = idx / 80, m2 = idx % 80;
    int tau = tt0 + t2;
    if (tau <= 1998) pv[((size_t)(tau + 1) * 128 + b) * 128 + m2] = pl[t2][m2];
  }
}
// frames[t][col][m] (f32, stride 40960) -> out[b][m][t], coalesced both sides
__global__ void k_out(const unsigned char* __restrict__ ws, float* __restrict__ out) {
  __shared__ float tl[125][84];
  int b = blockIdx.x, tc = blockIdx.y;     // 128 x 16
  int t0 = tc * 125, tid = threadIdx.x;
  for (int i = tid; i < 125 * 80; i += 256) {
    int tt = i / 80, m = i % 80;
    tl[tt][m] = *(const float*)(ws + OFF_ENCB + (size_t)(t0 + tt) * 40960 +
                                (size_t)b * 320 + (size_t)m * 4);
  }
  __syncthreads();
  for (int m = 0; m < 80; ++m)
    for (int tt = tid; tt < 125; tt += 256)
      out[((size_t)b * 80 + m) * 2000 + t0 + tt] = tl[tt][m];
}

// ------------------------------ persistent kernel ---------------------------
__global__ __launch_bounds__(256, 1) void k_persist(unsigned char* __restrict__ ws,
                                                    const float* __restrict__ fc_b) {
  __shared__ float red[4][64][68];     // cross-wave K reduction
  __shared__ float fcred[4][16][68];   // fc partials

  const int tid = threadIdx.x, bid = blockIdx.x;
  const int w = tid >> 6, l = tid & 63;
  const int r15 = l & 15, khi = l >> 4;
  const bool isG1 = bid < 128;
  const int lb = bid & 127, rb = lb >> 1, cg = lb & 1;
  const bool fcB = (!isG1) && (lb < 12);
  const int u6 = lb >> 1;
  const int ecol = tid & 63, quad = tid >> 6;

  // ---------------- resident A fragments ----------------
  bf16x8 avr[4][16];
  bf16x8 avp[4];
#pragma unroll
  for (int i = 0; i < 4; ++i) {
    const size_t row = (size_t)(rb * 64 + 16 * i + r15);
    const unsigned char* pa =
        ws + (isG1 ? OFF_WTXT : OFF_WIH2) + row * 2048 + w * 512 + khi * 16;
    const unsigned char* ph =
        ws + (isG1 ? OFF_WHH1 : OFF_WHH2) + row * 2048 + w * 512 + khi * 16;
#pragma unroll
    for (int t = 0; t < 8; ++t) avr[i][t] = *(const bf16x8*)(pa + t * 64);
#pragma unroll
    for (int t = 0; t < 8; ++t) avr[i][8 + t] = *(const bf16x8*)(ph + t * 64);
    if (isG1)
      avp[i] = *(const bf16x8*)(ws + OFF_WPREV + row * 256 + w * 64 + khi * 16);
  }
  bf16x8 fcav[8];
  if (fcB) {
    const unsigned char* pf = ws + OFF_FCW + (size_t)(u6 * 16 + r15) * 2048 + w * 512 + khi * 16;
#pragma unroll
    for (int t = 0; t < 8; ++t) fcav[t] = *(const bf16x8*)(pf + t * 64);
  }
  // g1: pstyle -> registers (plain loads; region never overwritten)
  float pstb[4][4];
  if (isG1) {
    const float* PS = (const float*)(ws + OFF_PSTYLE);
#pragma unroll
    for (int g = 0; g < 4; ++g)
#pragma unroll
      for (int u = 0; u < 4; ++u)
        pstb[g][u] = PS[(size_t)(rb * 64 + 16 * g + quad * 4 + u) * 128 + cg * 64 + ecol];
  }

  // ---------------- per-lane B column bases ----------------
  size_t prevb[4], hb[4];
#pragma unroll
  for (int j = 0; j < 4; ++j) {
    int col = cg * 64 + 16 * j + r15;
    prevb[j] = (size_t)col * 256 + w * 64 + khi * 16;
    hb[j]    = (size_t)col * 2048 + w * 512 + khi * 16;   // also enc t-major slot offset
  }

  float fcbr[4];
#pragma unroll
  for (int q = 0; q < 4; ++q) {
    int m = u6 * 16 + quad * 4 + q;
    fcbr[q] = (fcB && m < 80) ? fc_b[m] : 0.f;
  }
  float cst[4] = {0.f, 0.f, 0.f, 0.f};
  const f32x4 zero4 = {0.f, 0.f, 0.f, 0.f};

  // epoch slot of THIS block; publish with RELEASE (agent)
  unsigned* myslot = (unsigned*)(ws + (isG1 ? OFF_EPG1 : OFF_EPG2) +
                                 (size_t)(cg * 64 + rb) * 64);
  auto epPub = [&](unsigned v) __attribute__((always_inline)) {
    __hip_atomic_store(myslot, v, __ATOMIC_RELEASE, __HIP_MEMORY_SCOPE_AGENT);
  };
  const unsigned* q1 = (const unsigned*)(ws + OFF_EPG1 + (size_t)(cg * 64 + l) * 64);
  const unsigned* q2 = (const unsigned*)(ws + OFF_EPG2 + (size_t)(cg * 64 + l) * 64);
  auto waitSlots = [&](unsigned t1, unsigned t2) __attribute__((always_inline)) {
    if (w == 0) {
      for (long it = 0; it < 4000000; ++it) {
        unsigned v1 = __hip_atomic_load(q1, __ATOMIC_RELAXED, __HIP_MEMORY_SCOPE_AGENT);
        unsigned v2 = __hip_atomic_load(q2, __ATOMIC_RELAXED, __HIP_MEMORY_SCOPE_AGENT);
        if (__all((v1 >= t1) && (v2 >= t2))) break;
        __builtin_amdgcn_s_sleep(2);
      }
    }
    __syncthreads();
  };

  // ---- init publish: epoch 1 == "finished iteration -1" ----
  __syncthreads();
  if (tid == 0) epPub(1u);

  bf16x8 bvr[4][4];

#pragma unroll 1
  for (int s = 0; s < NSUP; ++s) {
    const bool g1a = isG1 && (s <= 1999);
    const bool g2a = (!isG1) && (s >= 2) && (s <= 2001);   // gates2[s-2]
    const bool fca = fcB && (s >= 3) && (s <= 2002);       // frame[s-3]
    const bool g2run = g2a || fca;
    const int m3 = s % 3;

    if (g1a) {
      f32x4 acc[4][4];
#pragma unroll
      for (int i = 0; i < 4; ++i)
#pragma unroll
        for (int j = 0; j < 4; ++j) acc[i][j] = zero4;

      // ---- shadow statics: enc + prev (9 t) ----
      const unsigned char* encbase =
          (s < 399) ? (ws + OFF_ENCB + (size_t)s * 262144) : (ws + OFF_ENC399);
      const unsigned char *ep[4], *pp[4];
#pragma unroll
      for (int j = 0; j < 4; ++j) {
        ep[j] = encbase + hb[j];
        pp[j] = ws + OFF_PREV + (size_t)s * 32768 + prevb[j];
      }
      auto ISSs = [&](int t) __attribute__((always_inline)) {
        if (t < 8) {
#pragma unroll
          for (int j = 0; j < 4; ++j) { ldx4(bvr[t & 3][j], ep[j]); ep[j] += 64; }
        } else {
#pragma unroll
          for (int j = 0; j < 4; ++j) ldx4(bvr[t & 3][j], pp[j]);
        }
      };
      ISSs(0); ISSs(1); ISSs(2); ISSs(3);
#pragma unroll
      for (int t = 0; t < 9; ++t) {
        if (t <= 5) VMW(12);
        else if (t == 6) VMW(8);
        else if (t == 7) VMW(4);
        else VMW(0);
        __builtin_amdgcn_sched_barrier(0);
#pragma unroll
        for (int i = 0; i < 4; ++i)
#pragma unroll
          for (int j = 0; j < 4; ++j)
            acc[i][j] = __builtin_amdgcn_mfma_f32_16x16x32_bf16(
                (t < 8) ? avr[i][t] : avp[i], bvr[t & 3][j], acc[i][j], 0, 0, 0);
        if (t + 4 <= 8) ISSs(t + 4);
      }

      // ---- wait: own ring >= s+1, g2 >= s+1 (ring-3 reuse guard) ----
      waitSlots((unsigned)(s + 1), (unsigned)(s + 1));

      // ---- recurrent half: h1[s-1] (skip at s=0: h1[-1]=0) ----
      if (s > 0) {
        const unsigned char* hp[4];
        const unsigned char* h1r1 = ws + OFF_H1 + (size_t)((m3 + 2) % 3) * 262144;
#pragma unroll
        for (int j = 0; j < 4; ++j) hp[j] = h1r1 + hb[j];
        auto ISSh = [&](int t) __attribute__((always_inline)) {
#pragma unroll
          for (int j = 0; j < 4; ++j) { ldx4a(bvr[t & 3][j], hp[j]); hp[j] += 64; }
        };
        ISSh(0); ISSh(1); ISSh(2); ISSh(3);
#pragma unroll
        for (int t = 0; t < 8; ++t) {
          if (t <= 4) VMW(12);
          else if (t == 5) VMW(8);
          else if (t == 6) VMW(4);
          else VMW(0);
          __builtin_amdgcn_sched_barrier(0);
#pragma unroll
          for (int i = 0; i < 4; ++i)
#pragma unroll
            for (int j = 0; j < 4; ++j)
              acc[i][j] = __builtin_amdgcn_mfma_f32_16x16x32_bf16(avr[i][8 + t], bvr[t & 3][j],
                                                                  acc[i][j], 0, 0, 0);
          if (t + 4 <= 7) ISSh(t + 4);
        }
      }

      // ---- epilogue: reduce + LSTM + h1 store (slot s%3) ----
#pragma unroll
      for (int i = 0; i < 4; ++i)
#pragma unroll
        for (int j = 0; j < 4; ++j)
#pragma unroll
          for (int q = 0; q < 4; ++q)
            red[w][16 * i + khi * 4 + q][16 * j + r15] = acc[i][j][q];
      __syncthreads();
      {
        unsigned hm[4];
#pragma unroll
        for (int u = 0; u < 4; ++u) {
          float gt[4];
#pragma unroll
          for (int g = 0; g < 4; ++g) {
            int row = 16 * g + quad * 4 + u;
            gt[g] = red[0][row][ecol] + red[1][row][ecol] + red[2][row][ecol] +
                    red[3][row][ecol] + pstb[g][u];
          }
          float ci = sigm(gt[0]), cf = sigm(gt[1]), cgt = tanh_(gt[2]), co = sigm(gt[3]);
          cst[u] = cf * cst[u] + ci * cgt;
          hm[u] = f2bf(co * tanh_(cst[u]));
        }
        unsigned long long hv = (unsigned long long)(hm[0] | (hm[1] << 16)) |
                                ((unsigned long long)(hm[2] | (hm[3] << 16)) << 32);
        const void* ha = ws + OFF_H1 + (size_t)m3 * 262144 +
                         (size_t)(cg * 64 + ecol) * 2048 + (size_t)(rb * 16 + quad * 4) * 2;
        asm volatile("global_store_dwordx2 %0, %1, off sc1" ::"v"(ha), "v"(hv) : "memory");
      }
    } else if (g2run) {
      // ---- wait: g1 >= s (h1[s-2] ready), own ring >= s+1 ----
      waitSlots((unsigned)s, (unsigned)(s + 1));

      f32x4 acc[4][4];
      f32x4 facc[4];
#pragma unroll
      for (int i = 0; i < 4; ++i) {
        facc[i] = zero4;
#pragma unroll
        for (int j = 0; j < 4; ++j) acc[i][j] = zero4;
      }
      const unsigned char *p1[4], *p2[4];
      {
        const unsigned char* h1rd = ws + OFF_H1 + (size_t)((m3 + 1) % 3) * 262144;  // h1[s-2]
        const unsigned char* h2rd = ws + OFF_H2 + (size_t)((s + 1) & 1) * 262144;   // h2[s-3]
#pragma unroll
        for (int j = 0; j < 4; ++j) { p1[j] = h1rd + hb[j]; p2[j] = h2rd + hb[j]; }
      }
      auto ISS2 = [&](int t) __attribute__((always_inline)) {
        if (t < 8) {
#pragma unroll
          for (int j = 0; j < 4; ++j) { ldx4a(bvr[t & 3][j], p1[j]); p1[j] += 64; }
        } else {
#pragma unroll
          for (int j = 0; j < 4; ++j) { ldx4a(bvr[t & 3][j], p2[j]); p2[j] += 64; }
        }
      };
      ISS2(0); ISS2(1); ISS2(2); ISS2(3);
#pragma unroll
      for (int t = 0; t < 16; ++t) {
        if (t <= 12) VMW(12);
        else if (t == 13) VMW(8);
        else if (t == 14) VMW(4);
        else VMW(0);
        __builtin_amdgcn_sched_barrier(0);
        if (g2a) {
#pragma unroll
          for (int i = 0; i < 4; ++i)
#pragma unroll
            for (int j = 0; j < 4; ++j)
              acc[i][j] = __builtin_amdgcn_mfma_f32_16x16x32_bf16(avr[i][t], bvr[t & 3][j],
                                                                  acc[i][j], 0, 0, 0);
        }
        if (fca && t >= 8) {
#pragma unroll
          for (int j = 0; j < 4; ++j)
            facc[j] = __builtin_amdgcn_mfma_f32_16x16x32_bf16(fcav[t - 8], bvr[t & 3][j],
                                                              facc[j], 0, 0, 0);
        }
        if (t + 4 <= 15) ISS2(t + 4);
      }

      // ---- epilogues ----
      if (g2a) {
#pragma unroll
        for (int i = 0; i < 4; ++i)
#pragma unroll
          for (int j = 0; j < 4; ++j)
#pragma unroll
            for (int q = 0; q < 4; ++q)
              red[w][16 * i + khi * 4 + q][16 * j + r15] = acc[i][j][q];
      }
      if (fca) {
#pragma unroll
        for (int j = 0; j < 4; ++j)
#pragma unroll
          for (int q = 0; q < 4; ++q)
            fcred[w][khi * 4 + q][16 * j + r15] = facc[j][q];
      }
      __syncthreads();
      if (g2a) {
        const float* B2 = (const float*)(ws + OFF_BIAS2);
        float pb[4][4];
#pragma unroll
        for (int g = 0; g < 4; ++g)
#pragma unroll
          for (int u = 0; u < 4; ++u)
            pb[g][u] = B2[rb * 64 + 16 * g + quad * 4 + u];
        unsigned hm[4];
#pragma unroll
        for (int u = 0; u < 4; ++u) {
          float gt[4];
#pragma unroll
          for (int g = 0; g < 4; ++g) {
            int row = 16 * g + quad * 4 + u;
            gt[g] = red[0][row][ecol] + red[1][row][ecol] + red[2][row][ecol] +
                    red[3][row][ecol] + pb[g][u];
          }
          float ci = sigm(gt[0]), cf = sigm(gt[1]), cgt = tanh_(gt[2]), co = sigm(gt[3]);
          cst[u] = cf * cst[u] + ci * cgt;
          hm[u] = f2bf(co * tanh_(cst[u]));
        }
        unsigned long long hv = (unsigned long long)(hm[0] | (hm[1] << 16)) |
                                ((unsigned long long)(hm[2] | (hm[3] << 16)) << 32);
        const void* ha = ws + OFF_H2 + (size_t)(s & 1) * 262144 +
                         (size_t)(cg * 64 + ecol) * 2048 + (size_t)(rb * 16 + quad * 4) * 2;
        asm volatile("global_store_dwordx2 %0, %1, off sc1" ::"v"(ha), "v"(hv) : "memory");
      }
      if (fca) {
        const int t0 = s - 3;
        // dense staged frame: frames[t0][col][m] f32 (stride 40960 in ENCB region)
        float* fr = (float*)(ws + OFF_ENCB + (size_t)t0 * 40960);
#pragma unroll
        for (int q = 0; q < 4; ++q) {
          int m = u6 * 16 + quad * 4 + q;
          float v = fcred[0][quad * 4 + q][ecol] + fcred[1][quad * 4 + q][ecol] +
                    fcred[2][quad * 4 + q][ecol] + fcred[3][quad * 4 + q][ecol] + fcbr[q];
          if (m < 80) {
            const float* fa = fr + (size_t)(cg * 64 + ecol) * 80 + m;
            asm volatile("global_store_dword %0, %1, off sc1" ::"v"(fa), "v"(v) : "memory");
          }
        }
      }
    }

    // ---- publish epoch: drain block stores, then RELEASE store ----
    VMW(0);
    __syncthreads();
    if (tid == 0) epPub((unsigned)(s + 2));
  }
}

// --------------------------------- launcher ---------------------------------
extern "C" void kernel_launch(void* const* d_in, const int* in_sizes, int n_in,
                              void* d_out, int out_size, void* d_ws, size_t ws_size,
                              hipStream_t stream) {
  (void)in_sizes; (void)n_in; (void)out_size;
  const float* enc  = (const float*)d_in[0];
  const float* styl = (const float*)d_in[1];
  const float* mel  = (const float*)d_in[2];
  const float* Wih1 = (const float*)d_in[3];
  const float* Whh1 = (const float*)d_in[4];
  const float* bih1 = (const float*)d_in[5];
  const float* bhh1 = (const float*)d_in[6];
  const float* Wih2 = (const float*)d_in[7];
  const float* Whh2 = (const float*)d_in[8];
  const float* bih2 = (const float*)d_in[9];
  const float* bhh2 = (const float*)d_in[10];
  const float* fcw  = (const float*)d_in[11];
  const float* fcb  = (const float*)d_in[12];
  unsigned char* ws = (unsigned char*)d_ws;
  float* out = (float*)d_out;
  if (ws_size < WS_NEED) return;

  hipMemsetAsync(ws + OFF_PREV, 0, (size_t)(WS_NEED - OFF_PREV), stream);
  k_pack_w1<<<16384, 256, 0, stream>>>(Wih1, Whh1, ws);
  k_pack_w2<<<16384, 256, 0, stream>>>(Wih2, Whh2, ws);
  k_bias2<<<16, 256, 0, stream>>>(bih2, bhh2, ws);
  k_pack_wprev<<<2048, 256, 0, stream>>>(Wih1, ws);
  k_pack_fc<<<384, 256, 0, stream>>>(fcw, ws);
  k_styleT<<<160, 256, 0, stream>>>(styl, (float*)(ws + OFF_STYLET));
  k_pstyle<<<2048, 256, 0, stream>>>(Wih1, bih1, bhh1, (float*)(ws + OFF_STYLET), ws);
  k_pack_enc<<<51200, 256, 0, stream>>>(enc, ws);   // overwrites STYLET region (done with it)
  k_pack_prev<<<dim3(32, 128), 256, 0, stream>>>(mel, ws);
  k_persist<<<256, 256, 0, stream>>>(ws, fcb);
  k_out<<<dim3(128, 16), 256, 0, stream>>>(ws, out);
}

// Round 12
// 33466.879 us; speedup vs baseline: 1.0635x; 1.0635x over previous
//
#include <hip/hip_runtime.h>
#include <hip/hip_bf16.h>
#include <stdint.h>

// ---------------------------------------------------------------------------
// Persistent-kernel LSTM decoder for MI355X — v12: v10's decoupled rings with
// TRUE elasticity: h1 ring deepened to 8 slots (reuses the 2MB pstyle region
// after init; ordered by a one-time global init barrier built on v10's proven
// release/acquire primitives). g1 no longer waits on g2 each step:
//   g1@s: own>=s+1, g2>=max(1,s-4)   (ring-8 reuse guard; g2 may lag 6 steps)
//   g2@s: g1>=s,   own>=s+1          (computes gates2[s-2], fc frame[s-3])
// Sync: epoch publish = atomic RELEASE store (agent), polls = relaxed agent
// atomic loads. h traffic sc1 (MALL). Everything else identical to v10.
// ---------------------------------------------------------------------------

#define NSUP 2003

typedef __attribute__((ext_vector_type(8))) short bf16x8;
typedef __attribute__((ext_vector_type(4))) float f32x4;

// ws layout (bytes)
#define OFF_WTXT   0ull
#define OFF_WHH1   8388608ull
#define OFF_WPREV  16777216ull
#define OFF_WIH2   17825792ull
#define OFF_WHH2   26214400ull
#define OFF_FCW    34603008ull
#define OFF_BIAS2  34799616ull
#define OFF_PS_H1R 34816000ull    // pstyle at launch; h1 ring 8 x 262144 after init (exactly 2MB)
#define OFF_ENC    36913152ull
#define OFF_STYLET 141606912ull   // ENC tail scratch; overwritten by k_pack_enc
#define OFF_PREV   141770752ull
#define OFF_H2     208093184ull   // 2 slots x 262144
#define OFF_EPG1   208617472ull   // g1 epoch slots: 2cg x 64 x 64B
#define OFF_EPG2   208625664ull   // g2 epoch slots
#define WS_NEED    208717824ull

__device__ __forceinline__ unsigned short f2bf(float f) {
  __hip_bfloat16 b = __float2bfloat16(f);
  return *reinterpret_cast<unsigned short*>(&b);
}
__device__ __forceinline__ float sigm(float x) { return 1.f / (1.f + __expf(-x)); }
__device__ __forceinline__ float tanh_(float x) {
  x = fminf(15.f, fmaxf(-15.f, x));
  float e = __expf(2.f * x);
  return (e - 1.f) / (e + 1.f);
}
__device__ __forceinline__ int origRow(int rp) {
  return ((rp >> 4) & 3) * 1024 + (rp >> 6) * 16 + (rp & 15);
}

#define VMW(n) asm volatile("s_waitcnt vmcnt(" #n ")" ::: "memory")

__device__ __forceinline__ void ldx4(bf16x8& d, const void* p) {      // plain
  asm volatile("global_load_dwordx4 %0, %1, off" : "=v"(d) : "v"(p));
}
__device__ __forceinline__ void ldx4a(bf16x8& d, const void* p) {     // agent
  asm volatile("global_load_dwordx4 %0, %1, off sc1" : "=v"(d) : "v"(p));
}

// ------------------------------- pack kernels -------------------------------
__global__ void k_pack_w1(const float* __restrict__ wih1, const float* __restrict__ whh1,
                          unsigned char* __restrict__ ws) {
  int idx = blockIdx.x * 256 + threadIdx.x;            // 4096*1024
  int rp = idx >> 10, k = idx & 1023;
  int orig = origRow(rp);
  ((unsigned short*)(ws + OFF_WTXT))[idx] = f2bf(wih1[(size_t)orig * 1424 + k]);
  ((unsigned short*)(ws + OFF_WHH1))[idx] = f2bf(whh1[(size_t)orig * 1024 + k]);
}
__global__ void k_pack_w2(const float* __restrict__ wih2, const float* __restrict__ whh2,
                          unsigned char* __restrict__ ws) {
  int idx = blockIdx.x * 256 + threadIdx.x;
  int rp = idx >> 10, k = idx & 1023;
  int orig = origRow(rp);
  ((unsigned short*)(ws + OFF_WIH2))[idx] = f2bf(wih2[(size_t)orig * 1024 + k]);
  ((unsigned short*)(ws + OFF_WHH2))[idx] = f2bf(whh2[(size_t)orig * 1024 + k]);
}
__global__ void k_bias2(const float* __restrict__ bih2, const float* __restrict__ bhh2,
                        unsigned char* __restrict__ ws) {
  int rp = blockIdx.x * 256 + threadIdx.x;
  if (rp >= 4096) return;
  int orig = origRow(rp);
  ((float*)(ws + OFF_BIAS2))[rp] = bih2[orig] + bhh2[orig];
}
__global__ void k_pack_wprev(const float* __restrict__ wih1, unsigned char* __restrict__ ws) {
  int idx = blockIdx.x * 256 + threadIdx.x;            // 4096*128
  int rp = idx >> 7, k = idx & 127;
  int orig = origRow(rp);
  ((unsigned short*)(ws + OFF_WPREV))[idx] =
      (k < 80) ? f2bf(wih1[(size_t)orig * 1424 + 1344 + k]) : (unsigned short)0;
}
__global__ void k_pack_fc(const float* __restrict__ fcw, unsigned char* __restrict__ ws) {
  int idx = blockIdx.x * 256 + threadIdx.x;            // 96*1024
  int r = idx >> 10, k = idx & 1023;
  ((unsigned short*)(ws + OFF_FCW))[idx] =
      (r < 80) ? f2bf(fcw[(size_t)r * 1024 + k]) : (unsigned short)0;
}
__global__ void k_pack_enc(const float* __restrict__ enc, unsigned char* __restrict__ ws) {
  size_t i = (size_t)blockIdx.x * 256 + threadIdx.x;   // 13,107,200 float4's
  float4 v = ((const float4*)enc)[i];
  union { unsigned short u[4]; unsigned long long ll; } z;
  z.u[0] = f2bf(v.x); z.u[1] = f2bf(v.y); z.u[2] = f2bf(v.z); z.u[3] = f2bf(v.w);
  ((unsigned long long*)(ws + OFF_ENC))[i] = z.ll;
}
__global__ void k_styleT(const float* __restrict__ style, float* __restrict__ sT) {
  int idx = blockIdx.x * 256 + threadIdx.x;            // 320*128
  int j = idx >> 7, n = idx & 127;
  sT[idx] = style[n * 320 + j];
}
__global__ void k_pstyle(const float* __restrict__ wih1, const float* __restrict__ bih1,
                         const float* __restrict__ bhh1, const float* __restrict__ sT,
                         unsigned char* __restrict__ ws) {
  int n = threadIdx.x & 127, rsub = threadIdx.x >> 7;
  int rp = blockIdx.x * 2 + rsub;
  int orig = origRow(rp);
  const float* wr = wih1 + (size_t)orig * 1424 + 1024;
  float a0 = 0.f, a1 = 0.f, a2 = 0.f, a3 = 0.f;
  for (int j = 0; j < 320; j += 4) {
    a0 += wr[j + 0] * sT[(j + 0) * 128 + n];
    a1 += wr[j + 1] * sT[(j + 1) * 128 + n];
    a2 += wr[j + 2] * sT[(j + 2) * 128 + n];
    a3 += wr[j + 3] * sT[(j + 3) * 128 + n];
  }
  ((float*)(ws + OFF_PS_H1R))[rp * 128 + n] = (a0 + a1) + (a2 + a3) + bih1[orig] + bhh1[orig];
}
__global__ void k_pack_prev(const float* __restrict__ mel, unsigned char* __restrict__ ws) {
  __shared__ unsigned short pl[64][80];
  int b = blockIdx.y, tt0 = blockIdx.x * 64;
  int tid = threadIdx.x;
  int ttl = tid & 63, mi = tid >> 6;
  for (int m = mi; m < 80; m += 4) {
    int tau = tt0 + ttl;
    if (tau <= 1998) pl[ttl][m] = f2bf(mel[((size_t)b * 80 + m) * 2000 + tau]);
  }
  __syncthreads();
  unsigned short* pv = (unsigned short*)(ws + OFF_PREV);
  for (int idx = tid; idx < 64 * 80; idx += 256) {
    int t2 = idx / 80, m2 = idx % 80;
    int tau = tt0 + t2;
    if (tau <= 1998) pv[((size_t)(tau + 1) * 128 + b) * 128 + m2] = pl[t2][m2];
  }
}

// ------------------------------ persistent kernel ---------------------------
__global__ __launch_bounds__(256, 1) void k_persist(unsigned char* __restrict__ ws,
                                                    float* __restrict__ out,
                                                    const float* __restrict__ fc_b) {
  __shared__ float red[4][64][68];     // cross-wave K reduction
  __shared__ float fcred[4][16][68];   // fc partials

  const int tid = threadIdx.x, bid = blockIdx.x;
  const int w = tid >> 6, l = tid & 63;
  const int r15 = l & 15, khi = l >> 4;
  const bool isG1 = bid < 128;
  const int lb = bid & 127, rb = lb >> 1, cg = lb & 1;
  const bool fcB = (!isG1) && (lb < 12);
  const int u6 = lb >> 1;
  const int ecol = tid & 63, quad = tid >> 6;

  // ---------------- resident A fragments ----------------
  bf16x8 avr[4][16];
  bf16x8 avp[4];
#pragma unroll
  for (int i = 0; i < 4; ++i) {
    const size_t row = (size_t)(rb * 64 + 16 * i + r15);
    const unsigned char* pa =
        ws + (isG1 ? OFF_WTXT : OFF_WIH2) + row * 2048 + w * 512 + khi * 16;
    const unsigned char* ph =
        ws + (isG1 ? OFF_WHH1 : OFF_WHH2) + row * 2048 + w * 512 + khi * 16;
#pragma unroll
    for (int t = 0; t < 8; ++t) avr[i][t] = *(const bf16x8*)(pa + t * 64);
#pragma unroll
    for (int t = 0; t < 8; ++t) avr[i][8 + t] = *(const bf16x8*)(ph + t * 64);
    if (isG1)
      avp[i] = *(const bf16x8*)(ws + OFF_WPREV + row * 256 + w * 64 + khi * 16);
  }
  bf16x8 fcav[8];
  if (fcB) {
    const unsigned char* pf = ws + OFF_FCW + (size_t)(u6 * 16 + r15) * 2048 + w * 512 + khi * 16;
#pragma unroll
    for (int t = 0; t < 8; ++t) fcav[t] = *(const bf16x8*)(pf + t * 64);
  }
  // g1: pstyle -> registers (plain loads; region becomes the h1 ring after the
  // global init barrier below)
  float pstb[4][4];
  if (isG1) {
    const float* PS = (const float*)(ws + OFF_PS_H1R);
#pragma unroll
    for (int g = 0; g < 4; ++g)
#pragma unroll
      for (int u = 0; u < 4; ++u)
        pstb[g][u] = PS[(size_t)(rb * 64 + 16 * g + quad * 4 + u) * 128 + cg * 64 + ecol];
  }

  // ---------------- per-lane B column bases ----------------
  size_t encb[4], prevb[4], hb[4];
#pragma unroll
  for (int j = 0; j < 4; ++j) {
    int col = cg * 64 + 16 * j + r15;
    encb[j]  = (size_t)col * 819200 + w * 512 + khi * 16;
    prevb[j] = (size_t)col * 256 + w * 64 + khi * 16;
    hb[j]    = (size_t)col * 2048 + w * 512 + khi * 16;
  }

  float fcbr[4];
#pragma unroll
  for (int q = 0; q < 4; ++q) {
    int m = u6 * 16 + quad * 4 + q;
    fcbr[q] = (fcB && m < 80) ? fc_b[m] : 0.f;
  }
  float cst[4] = {0.f, 0.f, 0.f, 0.f};
  const f32x4 zero4 = {0.f, 0.f, 0.f, 0.f};

  // epoch slot of THIS block; publish with RELEASE (agent)
  unsigned* myslot = (unsigned*)(ws + (isG1 ? OFF_EPG1 : OFF_EPG2) +
                                 (size_t)(cg * 64 + rb) * 64);
  auto epPub = [&](unsigned v) __attribute__((always_inline)) {
    __hip_atomic_store(myslot, v, __ATOMIC_RELEASE, __HIP_MEMORY_SCOPE_AGENT);
  };
  const unsigned* q1 = (const unsigned*)(ws + OFF_EPG1 + (size_t)(cg * 64 + l) * 64);
  const unsigned* q2 = (const unsigned*)(ws + OFF_EPG2 + (size_t)(cg * 64 + l) * 64);
  auto waitSlots = [&](unsigned t1, unsigned t2) __attribute__((always_inline)) {
    if (w == 0) {
      for (long it = 0; it < 4000000; ++it) {
        unsigned v1 = __hip_atomic_load(q1, __ATOMIC_RELAXED, __HIP_MEMORY_SCOPE_AGENT);
        unsigned v2 = __hip_atomic_load(q2, __ATOMIC_RELAXED, __HIP_MEMORY_SCOPE_AGENT);
        if (__all((v1 >= t1) && (v2 >= t2))) break;
        __builtin_amdgcn_s_sleep(2);
      }
    }
    __syncthreads();
  };

  // ---- init publish: epoch 1 == "registers loaded, pstyle consumed" ----
  __syncthreads();
  if (tid == 0) epPub(1u);

  // ---- ONE-TIME GLOBAL INIT BARRIER (all 256 blocks, both cgs): orders every
  // pstyle read before any h1-ring store. Built on the proven atomic
  // release/acquire primitives (v8/v9's plain-store version raced). ----
  {
    if (w == 0) {
      const unsigned* a0 = (const unsigned*)(ws + OFF_EPG1 + (size_t)l * 64);
      const unsigned* a1 = (const unsigned*)(ws + OFF_EPG1 + (size_t)(64 + l) * 64);
      const unsigned* b0 = (const unsigned*)(ws + OFF_EPG2 + (size_t)l * 64);
      const unsigned* b1 = (const unsigned*)(ws + OFF_EPG2 + (size_t)(64 + l) * 64);
      for (long it = 0; it < 8000000; ++it) {
        unsigned v0 = __hip_atomic_load(a0, __ATOMIC_RELAXED, __HIP_MEMORY_SCOPE_AGENT);
        unsigned v1 = __hip_atomic_load(a1, __ATOMIC_RELAXED, __HIP_MEMORY_SCOPE_AGENT);
        unsigned v2 = __hip_atomic_load(b0, __ATOMIC_RELAXED, __HIP_MEMORY_SCOPE_AGENT);
        unsigned v3 = __hip_atomic_load(b1, __ATOMIC_RELAXED, __HIP_MEMORY_SCOPE_AGENT);
        if (__all((v0 >= 1u) && (v1 >= 1u) && (v2 >= 1u) && (v3 >= 1u))) break;
        __builtin_amdgcn_s_sleep(2);
      }
    }
    __syncthreads();
  }

  bf16x8 bvr[4][4];

#pragma unroll 1
  for (int s = 0; s < NSUP; ++s) {
    const bool g1a = isG1 && (s <= 1999);
    const bool g2a = (!isG1) && (s >= 2) && (s <= 2001);   // gates2[s-2]
    const bool fca = fcB && (s >= 3) && (s <= 2002);       // frame[s-3]
    const bool g2run = g2a || fca;

    if (g1a) {
      f32x4 acc[4][4];
#pragma unroll
      for (int i = 0; i < 4; ++i)
#pragma unroll
        for (int j = 0; j < 4; ++j) acc[i][j] = zero4;

      // ---- shadow statics: enc + prev (9 t) ----
      const int tp = (s < 399) ? s : 399;
      const unsigned char *ep[4], *pp[4];
#pragma unroll
      for (int j = 0; j < 4; ++j) {
        ep[j] = ws + OFF_ENC + encb[j] + (size_t)tp * 2048;
        pp[j] = ws + OFF_PREV + (size_t)s * 32768 + prevb[j];
      }
      auto ISSs = [&](int t) __attribute__((always_inline)) {
        if (t < 8) {
#pragma unroll
          for (int j = 0; j < 4; ++j) { ldx4(bvr[t & 3][j], ep[j]); ep[j] += 64; }
        } else {
#pragma unroll
          for (int j = 0; j < 4; ++j) ldx4(bvr[t & 3][j], pp[j]);
        }
      };
      ISSs(0); ISSs(1); ISSs(2); ISSs(3);
#pragma unroll
      for (int t = 0; t < 9; ++t) {
        if (t <= 5) VMW(12);
        else if (t == 6) VMW(8);
        else if (t == 7) VMW(4);
        else VMW(0);
        __builtin_amdgcn_sched_barrier(0);
#pragma unroll
        for (int i = 0; i < 4; ++i)
#pragma unroll
          for (int j = 0; j < 4; ++j)
            acc[i][j] = __builtin_amdgcn_mfma_f32_16x16x32_bf16(
                (t < 8) ? avr[i][t] : avp[i], bvr[t & 3][j], acc[i][j], 0, 0, 0);
        if (t + 4 <= 8) ISSs(t + 4);
      }

      // ---- wait: own ring >= s+1; g2 only for ring-8 reuse (lag <= 6) ----
      {
        unsigned t2 = (s >= 5) ? (unsigned)(s - 4) : 1u;
        waitSlots((unsigned)(s + 1), t2);
      }

      // ---- recurrent half: h1[s-1] (skip at s=0: h1[-1]=0) ----
      if (s > 0) {
        const unsigned char* hp[4];
        const unsigned char* h1r1 = ws + OFF_PS_H1R + (size_t)((s - 1) & 7) * 262144;
#pragma unroll
        for (int j = 0; j < 4; ++j) hp[j] = h1r1 + hb[j];
        auto ISSh = [&](int t) __attribute__((always_inline)) {
#pragma unroll
          for (int j = 0; j < 4; ++j) { ldx4a(bvr[t & 3][j], hp[j]); hp[j] += 64; }
        };
        ISSh(0); ISSh(1); ISSh(2); ISSh(3);
#pragma unroll
        for (int t = 0; t < 8; ++t) {
          if (t <= 4) VMW(12);
          else if (t == 5) VMW(8);
          else if (t == 6) VMW(4);
          else VMW(0);
          __builtin_amdgcn_sched_barrier(0);
#pragma unroll
          for (int i = 0; i < 4; ++i)
#pragma unroll
            for (int j = 0; j < 4; ++j)
              acc[i][j] = __builtin_amdgcn_mfma_f32_16x16x32_bf16(avr[i][8 + t], bvr[t & 3][j],
                                                                  acc[i][j], 0, 0, 0);
          if (t + 4 <= 7) ISSh(t + 4);
        }
      }

      // ---- epilogue: reduce + LSTM + h1 store (slot s&7) ----
#pragma unroll
      for (int i = 0; i < 4; ++i)
#pragma unroll
        for (int j = 0; j < 4; ++j)
#pragma unroll
          for (int q = 0; q < 4; ++q)
            red[w][16 * i + khi * 4 + q][16 * j + r15] = acc[i][j][q];
      __syncthreads();
      {
        unsigned hm[4];
#pragma unroll
        for (int u = 0; u < 4; ++u) {
          float gt[4];
#pragma unroll
          for (int g = 0; g < 4; ++g) {
            int row = 16 * g + quad * 4 + u;
            gt[g] = red[0][row][ecol] + red[1][row][ecol] + red[2][row][ecol] +
                    red[3][row][ecol] + pstb[g][u];
          }
          float ci = sigm(gt[0]), cf = sigm(gt[1]), cgt = tanh_(gt[2]), co = sigm(gt[3]);
          cst[u] = cf * cst[u] + ci * cgt;
          hm[u] = f2bf(co * tanh_(cst[u]));
        }
        unsigned long long hv = (unsigned long long)(hm[0] | (hm[1] << 16)) |
                                ((unsigned long long)(hm[2] | (hm[3] << 16)) << 32);
        const void* ha = ws + OFF_PS_H1R + (size_t)(s & 7) * 262144 +
                         (size_t)(cg * 64 + ecol) * 2048 + (size_t)(rb * 16 + quad * 4) * 2;
        asm volatile("global_store_dwordx2 %0, %1, off sc1" ::"v"(ha), "v"(hv) : "memory");
      }
    } else if (g2run) {
      // ---- wait: g1 >= s (h1[s-2] ready), own ring >= s+1 ----
      waitSlots((unsigned)s, (unsigned)(s + 1));

      f32x4 acc[4][4];
      f32x4 facc[4];
#pragma unroll
      for (int i = 0; i < 4; ++i) {
        facc[i] = zero4;
#pragma unroll
        for (int j = 0; j < 4; ++j) acc[i][j] = zero4;
      }
      const unsigned char *p1[4], *p2[4];
      {
        const unsigned char* h1rd = ws + OFF_PS_H1R + (size_t)((s - 2) & 7) * 262144;  // h1[s-2]
        const unsigned char* h2rd = ws + OFF_H2 + (size_t)((s + 1) & 1) * 262144;      // h2[s-3]
#pragma unroll
        for (int j = 0; j < 4; ++j) { p1[j] = h1rd + hb[j]; p2[j] = h2rd + hb[j]; }
      }
      auto ISS2 = [&](int t) __attribute__((always_inline)) {
        if (t < 8) {
#pragma unroll
          for (int j = 0; j < 4; ++j) { ldx4a(bvr[t & 3][j], p1[j]); p1[j] += 64; }
        } else {
#pragma unroll
          for (int j = 0; j < 4; ++j) { ldx4a(bvr[t & 3][j], p2[j]); p2[j] += 64; }
        }
      };
      ISS2(0); ISS2(1); ISS2(2); ISS2(3);
#pragma unroll
      for (int t = 0; t < 16; ++t) {
        if (t <= 12) VMW(12);
        else if (t == 13) VMW(8);
        else if (t == 14) VMW(4);
        else VMW(0);
        __builtin_amdgcn_sched_barrier(0);
        if (g2a) {
#pragma unroll
          for (int i = 0; i < 4; ++i)
#pragma unroll
            for (int j = 0; j < 4; ++j)
              acc[i][j] = __builtin_amdgcn_mfma_f32_16x16x32_bf16(avr[i][t], bvr[t & 3][j],
                                                                  acc[i][j], 0, 0, 0);
        }
        if (fca && t >= 8) {
#pragma unroll
          for (int j = 0; j < 4; ++j)
            facc[j] = __builtin_amdgcn_mfma_f32_16x16x32_bf16(fcav[t - 8], bvr[t & 3][j],
                                                              facc[j], 0, 0, 0);
        }
        if (t + 4 <= 15) ISS2(t + 4);
      }

      // ---- epilogues ----
      if (g2a) {
#pragma unroll
        for (int i = 0; i < 4; ++i)
#pragma unroll
          for (int j = 0; j < 4; ++j)
#pragma unroll
            for (int q = 0; q < 4; ++q)
              red[w][16 * i + khi * 4 + q][16 * j + r15] = acc[i][j][q];
      }
      if (fca) {
#pragma unroll
        for (int j = 0; j < 4; ++j)
#pragma unroll
          for (int q = 0; q < 4; ++q)
            fcred[w][khi * 4 + q][16 * j + r15] = facc[j][q];
      }
      __syncthreads();
      if (g2a) {
        const float* B2 = (const float*)(ws + OFF_BIAS2);
        float pb[4][4];
#pragma unroll
        for (int g = 0; g < 4; ++g)
#pragma unroll
          for (int u = 0; u < 4; ++u)
            pb[g][u] = B2[rb * 64 + 16 * g + quad * 4 + u];
        unsigned hm[4];
#pragma unroll
        for (int u = 0; u < 4; ++u) {
          float gt[4];
#pragma unroll
          for (int g = 0; g < 4; ++g) {
            int row = 16 * g + quad * 4 + u;
            gt[g] = red[0][row][ecol] + red[1][row][ecol] + red[2][row][ecol] +
                    red[3][row][ecol] + pb[g][u];
          }
          float ci = sigm(gt[0]), cf = sigm(gt[1]), cgt = tanh_(gt[2]), co = sigm(gt[3]);
          cst[u] = cf * cst[u] + ci * cgt;
          hm[u] = f2bf(co * tanh_(cst[u]));
        }
        unsigned long long hv = (unsigned long long)(hm[0] | (hm[1] << 16)) |
                                ((unsigned long long)(hm[2] | (hm[3] << 16)) << 32);
        const void* ha = ws + OFF_H2 + (size_t)(s & 1) * 262144 +
                         (size_t)(cg * 64 + ecol) * 2048 + (size_t)(rb * 16 + quad * 4) * 2;
        asm volatile("global_store_dwordx2 %0, %1, off sc1" ::"v"(ha), "v"(hv) : "memory");
      }
      if (fca) {
        const int t0 = s - 3;
#pragma unroll
        for (int q = 0; q < 4; ++q) {
          int m = u6 * 16 + quad * 4 + q;
          float v = fcred[0][quad * 4 + q][ecol] + fcred[1][quad * 4 + q][ecol] +
                    fcred[2][quad * 4 + q][ecol] + fcred[3][quad * 4 + q][ecol] + fcbr[q];
          if (m < 80) out[((size_t)(cg * 64 + ecol) * 80 + m) * 2000 + t0] = v;
        }
      }
    }

    // ---- publish epoch: drain block stores, then RELEASE store ----
    VMW(0);
    __syncthreads();
    if (tid == 0) epPub((unsigned)(s + 2));
  }
}

// --------------------------------- launcher ---------------------------------
extern "C" void kernel_launch(void* const* d_in, const int* in_sizes, int n_in,
                              void* d_out, int out_size, void* d_ws, size_t ws_size,
                              hipStream_t stream) {
  (void)in_sizes; (void)n_in; (void)out_size;
  const float* enc  = (const float*)d_in[0];
  const float* styl = (const float*)d_in[1];
  const float* mel  = (const float*)d_in[2];
  const float* Wih1 = (const float*)d_in[3];
  const float* Whh1 = (const float*)d_in[4];
  const float* bih1 = (const float*)d_in[5];
  const float* bhh1 = (const float*)d_in[6];
  const float* Wih2 = (const float*)d_in[7];
  const float* Whh2 = (const float*)d_in[8];
  const float* bih2 = (const float*)d_in[9];
  const float* bhh2 = (const float*)d_in[10];
  const float* fcw  = (const float*)d_in[11];
  const float* fcb  = (const float*)d_in[12];
  unsigned char* ws = (unsigned char*)d_ws;
  float* out = (float*)d_out;
  if (ws_size < WS_NEED) return;

  hipMemsetAsync(ws + OFF_PREV, 0, (size_t)(WS_NEED - OFF_PREV), stream);
  k_pack_w1<<<16384, 256, 0, stream>>>(Wih1, Whh1, ws);
  k_pack_w2<<<16384, 256, 0, stream>>>(Wih2, Whh2, ws);
  k_bias2<<<16, 256, 0, stream>>>(bih2, bhh2, ws);
  k_pack_wprev<<<2048, 256, 0, stream>>>(Wih1, ws);
  k_pack_fc<<<384, 256, 0, stream>>>(fcw, ws);
  k_styleT<<<160, 256, 0, stream>>>(styl, (float*)(ws + OFF_STYLET));
  k_pstyle<<<2048, 256, 0, stream>>>(Wih1, bih1, bhh1, (float*)(ws + OFF_STYLET), ws);
  k_pack_enc<<<51200, 256, 0, stream>>>(enc, ws);   // overwrites STYLET region (done with it)
  k_pack_prev<<<dim3(32, 128), 256, 0, stream>>>(mel, ws);
  k_persist<<<256, 256, 0, stream>>>(ws, out, fcb);
}

// Round 13
// 26694.553 us; speedup vs baseline: 1.3333x; 1.2537x over previous
//
#include <hip/hip_runtime.h>
#include <hip/hip_bf16.h>
#include <stdint.h>

// ---------------------------------------------------------------------------
// Persistent-kernel LSTM decoder for MI355X — v13: v12's elastic rings +
// FRAGMENT-PACKED data layout. h1/h2/enc/prev are stored in MFMA-B-fragment
// order H[cg][w][t][j][lane*16B], so every K-loop load is 64 lanes x 16B
// FULLY CONTIGUOUS (1KB per load, 100% line utilization) instead of
// 2KB-strided 16B scatter. Producer epilogue writes one 8B store per thread.
// Epoch slots compacted to 4B stride (poll = 4 lines, was 64).
//   g1@s: own>=s+1, g2>=max(1,s-4)   (h1 ring-8 reuse guard)
//   g2@s: g1>=s,   own>=s+1          (computes gates2[s-2], fc frame[s-3])
// ---------------------------------------------------------------------------

#define NSUP 2003

typedef __attribute__((ext_vector_type(8))) short bf16x8;
typedef __attribute__((ext_vector_type(4))) float f32x4;

// ws layout (bytes)
#define OFF_WTXT   0ull
#define OFF_WHH1   8388608ull
#define OFF_WPREV  16777216ull
#define OFF_WIH2   17825792ull
#define OFF_WHH2   26214400ull
#define OFF_FCW    34603008ull
#define OFF_BIAS2  34799616ull
#define OFF_PS_H1R 34816000ull    // pstyle at launch; h1 ring 8 x 262144 after init
#define OFF_ENC    36913152ull    // 400 slices x 262144, fragment-packed
#define OFF_STYLET 141606912ull   // ENC tail scratch; overwritten by k_pack_enc
#define OFF_PREV   141770752ull   // 2001+ tau x 32768, fragment-packed
#define OFF_H2     208093184ull   // 2 slots x 262144, fragment-packed
#define OFF_EPG1   208617472ull   // g1 epochs: 128 x 4B
#define OFF_EPG2   208621568ull   // g2 epochs: 128 x 4B
#define WS_NEED    208717824ull

__device__ __forceinline__ unsigned short f2bf(float f) {
  __hip_bfloat16 b = __float2bfloat16(f);
  return *reinterpret_cast<unsigned short*>(&b);
}
__device__ __forceinline__ float sigm(float x) { return 1.f / (1.f + __expf(-x)); }
__device__ __forceinline__ float tanh_(float x) {
  x = fminf(15.f, fmaxf(-15.f, x));
  float e = __expf(2.f * x);
  return (e - 1.f) / (e + 1.f);
}
__device__ __forceinline__ int origRow(int rp) {
  return ((rp >> 4) & 3) * 1024 + (rp >> 6) * 16 + (rp & 15);
}

#define VMW(n) asm volatile("s_waitcnt vmcnt(" #n ")" ::: "memory")

__device__ __forceinline__ void ldx4(bf16x8& d, const void* p) {      // plain
  asm volatile("global_load_dwordx4 %0, %1, off" : "=v"(d) : "v"(p));
}
__device__ __forceinline__ void ldx4a(bf16x8& d, const void* p) {     // agent
  asm volatile("global_load_dwordx4 %0, %1, off sc1" : "=v"(d) : "v"(p));
}

// fragment address of unit n (0..1023), col c (0..127) within a 256KB slice:
//   cg=c>>6, w=n>>8, t=(n>>5)&7, khi=(n>>3)&3, e8=n&7, j=(c>>4)&3, r15=c&15
//   off = cg*131072 + w*32768 + t*4096 + j*1024 + (khi*16+r15)*16 + e8*2
__device__ __forceinline__ size_t fragOff(int c, int n) {
  return (size_t)(c >> 6) * 131072 + (size_t)(n >> 8) * 32768 +
         (size_t)((n >> 5) & 7) * 4096 + (size_t)((c >> 4) & 3) * 1024 +
         (size_t)((((n >> 3) & 3) * 16) + (c & 15)) * 16 + (size_t)(n & 7) * 2;
}

// ------------------------------- pack kernels -------------------------------
__global__ void k_pack_w1(const float* __restrict__ wih1, const float* __restrict__ whh1,
                          unsigned char* __restrict__ ws) {
  int idx = blockIdx.x * 256 + threadIdx.x;            // 4096*1024
  int rp = idx >> 10, k = idx & 1023;
  int orig = origRow(rp);
  ((unsigned short*)(ws + OFF_WTXT))[idx] = f2bf(wih1[(size_t)orig * 1424 + k]);
  ((unsigned short*)(ws + OFF_WHH1))[idx] = f2bf(whh1[(size_t)orig * 1024 + k]);
}
__global__ void k_pack_w2(const float* __restrict__ wih2, const float* __restrict__ whh2,
                          unsigned char* __restrict__ ws) {
  int idx = blockIdx.x * 256 + threadIdx.x;
  int rp = idx >> 10, k = idx & 1023;
  int orig = origRow(rp);
  ((unsigned short*)(ws + OFF_WIH2))[idx] = f2bf(wih2[(size_t)orig * 1024 + k]);
  ((unsigned short*)(ws + OFF_WHH2))[idx] = f2bf(whh2[(size_t)orig * 1024 + k]);
}
__global__ void k_bias2(const float* __restrict__ bih2, const float* __restrict__ bhh2,
                        unsigned char* __restrict__ ws) {
  int rp = blockIdx.x * 256 + threadIdx.x;
  if (rp >= 4096) return;
  int orig = origRow(rp);
  ((float*)(ws + OFF_BIAS2))[rp] = bih2[orig] + bhh2[orig];
}
__global__ void k_pack_wprev(const float* __restrict__ wih1, unsigned char* __restrict__ ws) {
  int idx = blockIdx.x * 256 + threadIdx.x;            // 4096*128
  int rp = idx >> 7, k = idx & 127;
  int orig = origRow(rp);
  ((unsigned short*)(ws + OFF_WPREV))[idx] =
      (k < 80) ? f2bf(wih1[(size_t)orig * 1424 + 1344 + k]) : (unsigned short)0;
}
__global__ void k_pack_fc(const float* __restrict__ fcw, unsigned char* __restrict__ ws) {
  int idx = blockIdx.x * 256 + threadIdx.x;            // 96*1024
  int r = idx >> 10, k = idx & 1023;
  ((unsigned short*)(ws + OFF_FCW))[idx] =
      (r < 80) ? f2bf(fcw[(size_t)r * 1024 + k]) : (unsigned short)0;
}
// fragment-packed enc: slice(tp) + fragOff(col=b, unit=u); 8B per thread-step
__global__ void k_pack_enc(const float* __restrict__ enc, unsigned char* __restrict__ ws) {
  size_t i = (size_t)blockIdx.x * 256 + threadIdx.x;   // 13,107,200 float4's
  float4 v = ((const float4*)enc)[i];
  union { unsigned short u[4]; unsigned long long ll; } z;
  z.u[0] = f2bf(v.x); z.u[1] = f2bf(v.y); z.u[2] = f2bf(v.z); z.u[3] = f2bf(v.w);
  int b  = (int)(i / (400 * 256));
  int tp = (int)((i >> 8) % 400);
  int u4 = (int)(i & 255);                             // units u4*4..+3 (one 8B chunk)
  *(unsigned long long*)(ws + OFF_ENC + (size_t)tp * 262144 + fragOff(b, u4 * 4)) = z.ll;
}
__global__ void k_styleT(const float* __restrict__ style, float* __restrict__ sT) {
  int idx = blockIdx.x * 256 + threadIdx.x;            // 320*128
  int j = idx >> 7, n = idx & 127;
  sT[idx] = style[n * 320 + j];
}
__global__ void k_pstyle(const float* __restrict__ wih1, const float* __restrict__ bih1,
                         const float* __restrict__ bhh1, const float* __restrict__ sT,
                         unsigned char* __restrict__ ws) {
  int n = threadIdx.x & 127, rsub = threadIdx.x >> 7;
  int rp = blockIdx.x * 2 + rsub;
  int orig = origRow(rp);
  const float* wr = wih1 + (size_t)orig * 1424 + 1024;
  float a0 = 0.f, a1 = 0.f, a2 = 0.f, a3 = 0.f;
  for (int j = 0; j < 320; j += 4) {
    a0 += wr[j + 0] * sT[(j + 0) * 128 + n];
    a1 += wr[j + 1] * sT[(j + 1) * 128 + n];
    a2 += wr[j + 2] * sT[(j + 2) * 128 + n];
    a3 += wr[j + 3] * sT[(j + 3) * 128 + n];
  }
  ((float*)(ws + OFF_PS_H1R))[rp * 128 + n] = (a0 + a1) + (a2 + a3) + bih1[orig] + bhh1[orig];
}
// fragment-packed prev: base + tau*32768; per tau: cg*16384 + w*4096 + j*1024
// + (khi*16+r15)*16 + e8*2 with m-unit: w=m>>5, khi=(m>>3)&3, e8=m&7
__global__ void k_pack_prev(const float* __restrict__ mel, unsigned char* __restrict__ ws) {
  __shared__ unsigned short pl[64][80];
  int b = blockIdx.y, tt0 = blockIdx.x * 64;
  int tid = threadIdx.x;
  int ttl = tid & 63, mi = tid >> 6;
  for (int m = mi; m < 80; m += 4) {
    int tau = tt0 + ttl;
    if (tau <= 1998) pl[ttl][m] = f2bf(mel[((size_t)b * 80 + m) * 2000 + tau]);
  }
  __syncthreads();
  for (int idx = tid; idx < 64 * 80; idx += 256) {
    int t2 = idx / 80, m = idx % 80;
    int tau = tt0 + t2;
    if (tau <= 1998) {
      size_t off = (size_t)(tau + 1) * 32768 + (size_t)(b >> 6) * 16384 +
                   (size_t)(m >> 5) * 4096 + (size_t)((b >> 4) & 3) * 1024 +
                   (size_t)((((m >> 3) & 3) * 16) + (b & 15)) * 16 + (size_t)(m & 7) * 2;
      *(unsigned short*)(ws + OFF_PREV + off) = pl[t2][m];
    }
  }
}

// ------------------------------ persistent kernel ---------------------------
__global__ __launch_bounds__(256, 1) void k_persist(unsigned char* __restrict__ ws,
                                                    float* __restrict__ out,
                                                    const float* __restrict__ fc_b) {
  __shared__ float red[4][64][68];     // cross-wave K reduction
  __shared__ float fcred[4][16][68];   // fc partials

  const int tid = threadIdx.x, bid = blockIdx.x;
  const int w = tid >> 6, l = tid & 63;
  const int r15 = l & 15, khi = l >> 4;
  const bool isG1 = bid < 128;
  const int lb = bid & 127, rb = lb >> 1, cg = lb & 1;
  const bool fcB = (!isG1) && (lb < 12);
  const int u6 = lb >> 1;
  const int ecol = tid & 63, quad = tid >> 6;

  // ---------------- resident A fragments ----------------
  bf16x8 avr[4][16];
  bf16x8 avp[4];
#pragma unroll
  for (int i = 0; i < 4; ++i) {
    const size_t row = (size_t)(rb * 64 + 16 * i + r15);
    const unsigned char* pa =
        ws + (isG1 ? OFF_WTXT : OFF_WIH2) + row * 2048 + w * 512 + khi * 16;
    const unsigned char* ph =
        ws + (isG1 ? OFF_WHH1 : OFF_WHH2) + row * 2048 + w * 512 + khi * 16;
#pragma unroll
    for (int t = 0; t < 8; ++t) avr[i][t] = *(const bf16x8*)(pa + t * 64);
#pragma unroll
    for (int t = 0; t < 8; ++t) avr[i][8 + t] = *(const bf16x8*)(ph + t * 64);
    if (isG1)
      avp[i] = *(const bf16x8*)(ws + OFF_WPREV + row * 256 + w * 64 + khi * 16);
  }
  bf16x8 fcav[8];
  if (fcB) {
    const unsigned char* pf = ws + OFF_FCW + (size_t)(u6 * 16 + r15) * 2048 + w * 512 + khi * 16;
#pragma unroll
    for (int t = 0; t < 8; ++t) fcav[t] = *(const bf16x8*)(pf + t * 64);
  }
  // g1: pstyle -> registers (plain loads; region becomes the h1 ring after the
  // global init barrier below)
  float pstb[4][4];
  if (isG1) {
    const float* PS = (const float*)(ws + OFF_PS_H1R);
#pragma unroll
    for (int g = 0; g < 4; ++g)
#pragma unroll
      for (int u = 0; u < 4; ++u)
        pstb[g][u] = PS[(size_t)(rb * 64 + 16 * g + quad * 4 + u) * 128 + cg * 64 + ecol];
  }

  // producer h-store fragment offset (one 8B store per thread; see header map)
  const size_t hfragOff = (size_t)cg * 131072 + (size_t)(rb >> 4) * 32768 +
                          (size_t)((rb >> 1) & 7) * 4096 + (size_t)(ecol >> 4) * 1024 +
                          (size_t)((((rb & 1) * 2 + (quad >> 1)) * 16) + (ecol & 15)) * 16 +
                          (size_t)(quad & 1) * 8;
  // consumer fragment base offset for this (cg, w) + lane
  const size_t cfrag = (size_t)cg * 131072 + (size_t)w * 32768 + (size_t)l * 16;

  float fcbr[4];
#pragma unroll
  for (int q = 0; q < 4; ++q) {
    int m = u6 * 16 + quad * 4 + q;
    fcbr[q] = (fcB && m < 80) ? fc_b[m] : 0.f;
  }
  float cst[4] = {0.f, 0.f, 0.f, 0.f};
  const f32x4 zero4 = {0.f, 0.f, 0.f, 0.f};

  // epoch slot of THIS block (4B stride); publish with RELEASE (agent)
  unsigned* myslot = (unsigned*)(ws + (isG1 ? OFF_EPG1 : OFF_EPG2) +
                                 (size_t)(cg * 64 + rb) * 4);
  auto epPub = [&](unsigned v) __attribute__((always_inline)) {
    __hip_atomic_store(myslot, v, __ATOMIC_RELEASE, __HIP_MEMORY_SCOPE_AGENT);
  };
  const unsigned* q1 = (const unsigned*)(ws + OFF_EPG1 + (size_t)(cg * 64 + l) * 4);
  const unsigned* q2 = (const unsigned*)(ws + OFF_EPG2 + (size_t)(cg * 64 + l) * 4);
  auto waitSlots = [&](unsigned t1, unsigned t2) __attribute__((always_inline)) {
    if (w == 0) {
      for (long it = 0; it < 4000000; ++it) {
        unsigned v1 = __hip_atomic_load(q1, __ATOMIC_RELAXED, __HIP_MEMORY_SCOPE_AGENT);
        unsigned v2 = __hip_atomic_load(q2, __ATOMIC_RELAXED, __HIP_MEMORY_SCOPE_AGENT);
        if (__all((v1 >= t1) && (v2 >= t2))) break;
        __builtin_amdgcn_s_sleep(2);
      }
    }
    __syncthreads();
  };

  // ---- init publish: epoch 1 == "registers loaded, pstyle consumed" ----
  __syncthreads();
  if (tid == 0) epPub(1u);

  // ---- ONE-TIME GLOBAL INIT BARRIER (all 256 blocks): orders every pstyle
  // read before any h1-ring store (atomic primitives; v8/v9 plain-store raced) ----
  {
    if (w == 0) {
      const unsigned* a0 = (const unsigned*)(ws + OFF_EPG1 + (size_t)l * 4);
      const unsigned* a1 = (const unsigned*)(ws + OFF_EPG1 + (size_t)(64 + l) * 4);
      const unsigned* b0 = (const unsigned*)(ws + OFF_EPG2 + (size_t)l * 4);
      const unsigned* b1 = (const unsigned*)(ws + OFF_EPG2 + (size_t)(64 + l) * 4);
      for (long it = 0; it < 8000000; ++it) {
        unsigned v0 = __hip_atomic_load(a0, __ATOMIC_RELAXED, __HIP_MEMORY_SCOPE_AGENT);
        unsigned v1 = __hip_atomic_load(a1, __ATOMIC_RELAXED, __HIP_MEMORY_SCOPE_AGENT);
        unsigned v2 = __hip_atomic_load(b0, __ATOMIC_RELAXED, __HIP_MEMORY_SCOPE_AGENT);
        unsigned v3 = __hip_atomic_load(b1, __ATOMIC_RELAXED, __HIP_MEMORY_SCOPE_AGENT);
        if (__all((v0 >= 1u) && (v1 >= 1u) && (v2 >= 1u) && (v3 >= 1u))) break;
        __builtin_amdgcn_s_sleep(2);
      }
    }
    __syncthreads();
  }

  bf16x8 bvr[4][4];

#pragma unroll 1
  for (int s = 0; s < NSUP; ++s) {
    const bool g1a = isG1 && (s <= 1999);
    const bool g2a = (!isG1) && (s >= 2) && (s <= 2001);   // gates2[s-2]
    const bool fca = fcB && (s >= 3) && (s <= 2002);       // frame[s-3]
    const bool g2run = g2a || fca;

    if (g1a) {
      f32x4 acc[4][4];
#pragma unroll
      for (int i = 0; i < 4; ++i)
#pragma unroll
        for (int j = 0; j < 4; ++j) acc[i][j] = zero4;

      // ---- shadow statics: enc + prev (9 t), contiguous 1KB loads ----
      const int tp = (s < 399) ? s : 399;
      const unsigned char* encw = ws + OFF_ENC + (size_t)tp * 262144 + cfrag;
      const unsigned char* prvw = ws + OFF_PREV + (size_t)s * 32768 +
                                  (size_t)cg * 16384 + (size_t)w * 4096 + (size_t)l * 16;
      const unsigned char *ep[4], *pp[4];
#pragma unroll
      for (int j = 0; j < 4; ++j) { ep[j] = encw + j * 1024; pp[j] = prvw + j * 1024; }
      auto ISSs = [&](int t) __attribute__((always_inline)) {
        if (t < 8) {
#pragma unroll
          for (int j = 0; j < 4; ++j) { ldx4(bvr[t & 3][j], ep[j]); ep[j] += 4096; }
        } else {
#pragma unroll
          for (int j = 0; j < 4; ++j) ldx4(bvr[t & 3][j], pp[j]);
        }
      };
      ISSs(0); ISSs(1); ISSs(2); ISSs(3);
#pragma unroll
      for (int t = 0; t < 9; ++t) {
        if (t <= 5) VMW(12);
        else if (t == 6) VMW(8);
        else if (t == 7) VMW(4);
        else VMW(0);
        __builtin_amdgcn_sched_barrier(0);
#pragma unroll
        for (int i = 0; i < 4; ++i)
#pragma unroll
          for (int j = 0; j < 4; ++j)
            acc[i][j] = __builtin_amdgcn_mfma_f32_16x16x32_bf16(
                (t < 8) ? avr[i][t] : avp[i], bvr[t & 3][j], acc[i][j], 0, 0, 0);
        if (t + 4 <= 8) ISSs(t + 4);
      }

      // ---- wait: own ring >= s+1; g2 only for ring-8 reuse (lag <= 6) ----
      {
        unsigned t2 = (s >= 5) ? (unsigned)(s - 4) : 1u;
        waitSlots((unsigned)(s + 1), t2);
      }

      // ---- recurrent half: h1[s-1], contiguous loads (skip at s=0) ----
      if (s > 0) {
        const unsigned char* h1w_ = ws + OFF_PS_H1R + (size_t)((s - 1) & 7) * 262144 + cfrag;
        const unsigned char* hp[4];
#pragma unroll
        for (int j = 0; j < 4; ++j) hp[j] = h1w_ + j * 1024;
        auto ISSh = [&](int t) __attribute__((always_inline)) {
#pragma unroll
          for (int j = 0; j < 4; ++j) { ldx4a(bvr[t & 3][j], hp[j]); hp[j] += 4096; }
        };
        ISSh(0); ISSh(1); ISSh(2); ISSh(3);
#pragma unroll
        for (int t = 0; t < 8; ++t) {
          if (t <= 4) VMW(12);
          else if (t == 5) VMW(8);
          else if (t == 6) VMW(4);
          else VMW(0);
          __builtin_amdgcn_sched_barrier(0);
#pragma unroll
          for (int i = 0; i < 4; ++i)
#pragma unroll
            for (int j = 0; j < 4; ++j)
              acc[i][j] = __builtin_amdgcn_mfma_f32_16x16x32_bf16(avr[i][8 + t], bvr[t & 3][j],
                                                                  acc[i][j], 0, 0, 0);
          if (t + 4 <= 7) ISSh(t + 4);
        }
      }

      // ---- epilogue: reduce + LSTM + h1 store (fragment-packed, slot s&7) ----
#pragma unroll
      for (int i = 0; i < 4; ++i)
#pragma unroll
        for (int j = 0; j < 4; ++j)
#pragma unroll
          for (int q = 0; q < 4; ++q)
            red[w][16 * i + khi * 4 + q][16 * j + r15] = acc[i][j][q];
      __syncthreads();
      {
        unsigned hm[4];
#pragma unroll
        for (int u = 0; u < 4; ++u) {
          float gt[4];
#pragma unroll
          for (int g = 0; g < 4; ++g) {
            int row = 16 * g + quad * 4 + u;
            gt[g] = red[0][row][ecol] + red[1][row][ecol] + red[2][row][ecol] +
                    red[3][row][ecol] + pstb[g][u];
          }
          float ci = sigm(gt[0]), cf = sigm(gt[1]), cgt = tanh_(gt[2]), co = sigm(gt[3]);
          cst[u] = cf * cst[u] + ci * cgt;
          hm[u] = f2bf(co * tanh_(cst[u]));
        }
        unsigned long long hv = (unsigned long long)(hm[0] | (hm[1] << 16)) |
                                ((unsigned long long)(hm[2] | (hm[3] << 16)) << 32);
        const void* ha = ws + OFF_PS_H1R + (size_t)(s & 7) * 262144 + hfragOff;
        asm volatile("global_store_dwordx2 %0, %1, off sc1" ::"v"(ha), "v"(hv) : "memory");
      }
    } else if (g2run) {
      // ---- wait: g1 >= s (h1[s-2] ready), own ring >= s+1 ----
      waitSlots((unsigned)s, (unsigned)(s + 1));

      f32x4 acc[4][4];
      f32x4 facc[4];
#pragma unroll
      for (int i = 0; i < 4; ++i) {
        facc[i] = zero4;
#pragma unroll
        for (int j = 0; j < 4; ++j) acc[i][j] = zero4;
      }
      const unsigned char *p1[4], *p2[4];
      {
        const unsigned char* h1rd = ws + OFF_PS_H1R + (size_t)((s - 2) & 7) * 262144 + cfrag;
        const unsigned char* h2rd = ws + OFF_H2 + (size_t)((s + 1) & 1) * 262144 + cfrag;
#pragma unroll
        for (int j = 0; j < 4; ++j) { p1[j] = h1rd + j * 1024; p2[j] = h2rd + j * 1024; }
      }
      auto ISS2 = [&](int t) __attribute__((always_inline)) {
        if (t < 8) {
#pragma unroll
          for (int j = 0; j < 4; ++j) { ldx4a(bvr[t & 3][j], p1[j]); p1[j] += 4096; }
        } else {
#pragma unroll
          for (int j = 0; j < 4; ++j) { ldx4a(bvr[t & 3][j], p2[j]); p2[j] += 4096; }
        }
      };
      ISS2(0); ISS2(1); ISS2(2); ISS2(3);
#pragma unroll
      for (int t = 0; t < 16; ++t) {
        if (t <= 12) VMW(12);
        else if (t == 13) VMW(8);
        else if (t == 14) VMW(4);
        else VMW(0);
        __builtin_amdgcn_sched_barrier(0);
        if (g2a) {
#pragma unroll
          for (int i = 0; i < 4; ++i)
#pragma unroll
            for (int j = 0; j < 4; ++j)
              acc[i][j] = __builtin_amdgcn_mfma_f32_16x16x32_bf16(avr[i][t], bvr[t & 3][j],
                                                                  acc[i][j], 0, 0, 0);
        }
        if (fca && t >= 8) {
#pragma unroll
          for (int j = 0; j < 4; ++j)
            facc[j] = __builtin_amdgcn_mfma_f32_16x16x32_bf16(fcav[t - 8], bvr[t & 3][j],
                                                              facc[j], 0, 0, 0);
        }
        if (t + 4 <= 15) ISS2(t + 4);
      }

      // ---- epilogues ----
      if (g2a) {
#pragma unroll
        for (int i = 0; i < 4; ++i)
#pragma unroll
          for (int j = 0; j < 4; ++j)
#pragma unroll
            for (int q = 0; q < 4; ++q)
              red[w][16 * i + khi * 4 + q][16 * j + r15] = acc[i][j][q];
      }
      if (fca) {
#pragma unroll
        for (int j = 0; j < 4; ++j)
#pragma unroll
          for (int q = 0; q < 4; ++q)
            fcred[w][khi * 4 + q][16 * j + r15] = facc[j][q];
      }
      __syncthreads();
      if (g2a) {
        const float* B2 = (const float*)(ws + OFF_BIAS2);
        float pb[4][4];
#pragma unroll
        for (int g = 0; g < 4; ++g)
#pragma unroll
          for (int u = 0; u < 4; ++u)
            pb[g][u] = B2[rb * 64 + 16 * g + quad * 4 + u];
        unsigned hm[4];
#pragma unroll
        for (int u = 0; u < 4; ++u) {
          float gt[4];
#pragma unroll
          for (int g = 0; g < 4; ++g) {
            int row = 16 * g + quad * 4 + u;
            gt[g] = red[0][row][ecol] + red[1][row][ecol] + red[2][row][ecol] +
                    red[3][row][ecol] + pb[g][u];
          }
          float ci = sigm(gt[0]), cf = sigm(gt[1]), cgt = tanh_(gt[2]), co = sigm(gt[3]);
          cst[u] = cf * cst[u] + ci * cgt;
          hm[u] = f2bf(co * tanh_(cst[u]));
        }
        unsigned long long hv = (unsigned long long)(hm[0] | (hm[1] << 16)) |
                                ((unsigned long long)(hm[2] | (hm[3] << 16)) << 32);
        const void* ha = ws + OFF_H2 + (size_t)(s & 1) * 262144 + hfragOff;
        asm volatile("global_store_dwordx2 %0, %1, off sc1" ::"v"(ha), "v"(hv) : "memory");
      }
      if (fca) {
        const int t0 = s - 3;
#pragma unroll
        for (int q = 0; q < 4; ++q) {
          int m = u6 * 16 + quad * 4 + q;
          float v = fcred[0][quad * 4 + q][ecol] + fcred[1][quad * 4 + q][ecol] +
                    fcred[2][quad * 4 + q][ecol] + fcred[3][quad * 4 + q][ecol] + fcbr[q];
          if (m < 80) out[((size_t)(cg * 64 + ecol) * 80 + m) * 2000 + t0] = v;
        }
      }
    }

    // ---- publish epoch: drain block stores, then RELEASE store ----
    VMW(0);
    __syncthreads();
    if (tid == 0) epPub((unsigned)(s + 2));
  }
}

// --------------------------------- launcher ---------------------------------
extern "C" void kernel_launch(void* const* d_in, const int* in_sizes, int n_in,
                              void* d_out, int out_size, void* d_ws, size_t ws_size,
                              hipStream_t stream) {
  (void)in_sizes; (void)n_in; (void)out_size;
  const float* enc  = (const float*)d_in[0];
  const float* styl = (const float*)d_in[1];
  const float* mel  = (const float*)d_in[2];
  const float* Wih1 = (const float*)d_in[3];
  const float* Whh1 = (const float*)d_in[4];
  const float* bih1 = (const float*)d_in[5];
  const float* bhh1 = (const float*)d_in[6];
  const float* Wih2 = (const float*)d_in[7];
  const float* Whh2 = (const float*)d_in[8];
  const float* bih2 = (const float*)d_in[9];
  const float* bhh2 = (const float*)d_in[10];
  const float* fcw  = (const float*)d_in[11];
  const float* fcb  = (const float*)d_in[12];
  unsigned char* ws = (unsigned char*)d_ws;
  float* out = (float*)d_out;
  if (ws_size < WS_NEED) return;

  hipMemsetAsync(ws + OFF_PREV, 0, (size_t)(WS_NEED - OFF_PREV), stream);
  k_pack_w1<<<16384, 256, 0, stream>>>(Wih1, Whh1, ws);
  k_pack_w2<<<16384, 256, 0, stream>>>(Wih2, Whh2, ws);
  k_bias2<<<16, 256, 0, stream>>>(bih2, bhh2, ws);
  k_pack_wprev<<<2048, 256, 0, stream>>>(Wih1, ws);
  k_pack_fc<<<384, 256, 0, stream>>>(fcw, ws);
  k_styleT<<<160, 256, 0, stream>>>(styl, (float*)(ws + OFF_STYLET));
  k_pstyle<<<2048, 256, 0, stream>>>(Wih1, bih1, bhh1, (float*)(ws + OFF_STYLET), ws);
  k_pack_enc<<<51200, 256, 0, stream>>>(enc, ws);   // overwrites STYLET region (done with it)
  k_pack_prev<<<dim3(32, 128), 256, 0, stream>>>(mel, ws);
  k_persist<<<256, 256, 0, stream>>>(ws, out, fcb);
}